// Round 8
// baseline (210.616 us; speedup 1.0000x reference)
//
#include <hip/hip_runtime.h>
#include <math.h>

#define HW 4096   // H*W = 64*64; B=4, C=64, H=W=64, L=4096

typedef short bf16x8 __attribute__((ext_vector_type(8)));
typedef float floatx4 __attribute__((ext_vector_type(4)));
typedef unsigned short u16x8 __attribute__((ext_vector_type(8)));

__device__ __forceinline__ unsigned short f2bf_rne(float x) {
    unsigned int u = __float_as_uint(x);
    unsigned int r = (u + 0x7FFFu + ((u >> 16) & 1u)) >> 16;
    return (unsigned short)r;
}
__device__ __forceinline__ float bf2f(unsigned short h) {
    return __uint_as_float(((unsigned int)h) << 16);
}

// async global->LDS, 16 B per lane; LDS dest is wave-uniform base + lane*16.
__device__ __forceinline__ void gload_lds16(const void* gptr, void* lptr) {
    auto g = (const __attribute__((address_space(1))) unsigned int*)(unsigned long long)(gptr);
    auto l = (__attribute__((address_space(3))) unsigned int*)(unsigned int)(unsigned long long)(lptr);
    __builtin_amdgcn_global_load_lds(g, l, 16, 0, 0);
}

// ---------------- prep: z=0 Q / z=1 K: split fp32 -> bf16 (hi,lo), transpose
// to [p][c], fused per-pixel squared norms. Row layout (192 shorts):
//   Aq[b][p] = [Qh | (unused) | Ql]   (gemm reads hi @ +0B, lo @ +256B)
//   Bq[b][p] = [Kh | Kl | (unused)]   (gemm reads hi @ +0B, lo @ +128B)
// z=2: transpose V -> VT[b][p][c] (f32) so gatherT reads channels contiguous.
__global__ __launch_bounds__(256)
void prep_kernel(const float* __restrict__ Q, const float* __restrict__ K,
                 const float* __restrict__ V,
                 unsigned short* __restrict__ Aq, unsigned short* __restrict__ Bq,
                 float* __restrict__ VT,
                 float* __restrict__ pix2q, float* __restrict__ pix2k) {
    __shared__ float sT[64][65];
    const int tid = threadIdx.x;
    const int p0 = blockIdx.x * 64;
    const int b = blockIdx.y;
    const int which = blockIdx.z;            // 0=Q, 1=K, 2=V
    const float* __restrict__ src = (which == 0) ? Q : ((which == 1) ? K : V);

#pragma unroll
    for (int it = 0; it < 16; ++it) {
        int idx = it * 256 + tid;
        int c = idx >> 6, x = idx & 63;
        sT[c][x] = src[((size_t)b * 64 + c) * HW + p0 + x];
    }
    __syncthreads();
    const int pp = tid >> 2, qt = tid & 3;

    if (which == 2) {                        // V: pure f32 transpose
        float* dst = VT + ((size_t)b * 4096 + p0 + pp) * 64 + qt * 16;
#pragma unroll
        for (int j = 0; j < 4; ++j) {
            float4 v = make_float4(sT[qt * 16 + 4 * j + 0][pp], sT[qt * 16 + 4 * j + 1][pp],
                                   sT[qt * 16 + 4 * j + 2][pp], sT[qt * 16 + 4 * j + 3][pp]);
            *(float4*)(dst + 4 * j) = v;
        }
        return;
    }

    const int isK = which;
    unsigned short* __restrict__ dst = isK ? Bq : Aq;
    float* __restrict__ pix2 = isK ? pix2k : pix2q;
    const size_t base = ((size_t)b * 4096 + p0 + pp) * 192;
    {
        float sq = 0.f;
        u16x8 hv[2], lv[2];
#pragma unroll
        for (int g = 0; g < 2; ++g)
#pragma unroll
            for (int j = 0; j < 8; ++j) {
                int c = qt * 16 + g * 8 + j;
                float x = sT[c][pp];
                sq = fmaf(x, x, sq);
                unsigned short h = f2bf_rne(x);
                hv[g][j] = h;
                lv[g][j] = f2bf_rne(x - bf2f(h));
            }
        sq += __shfl_xor(sq, 1, 64);
        sq += __shfl_xor(sq, 2, 64);
        if (qt == 0) pix2[(b << 12) + p0 + pp] = sq;
#pragma unroll
        for (int g = 0; g < 2; ++g) {
            int co = qt * 16 + g * 8;
            *(u16x8*)(dst + base + co)                     = hv[g];  // hi slice
            *(u16x8*)(dst + base + (isK ? 64 : 128) + co)  = lv[g];  // lo slice
        }
    }
}

// ---------------- patch reciprocal norms: 1/max(sqrt(3x3 box sum), 1e-12) ----
__global__ void patchnorm_kernel(const float* __restrict__ pix2q, const float* __restrict__ pix2k,
                                 float* __restrict__ rnq, float* __restrict__ rnk) {
    int idx = blockIdx.x * 256 + threadIdx.x;   // b*4096 + p
    int b = idx >> 12, p = idx & 4095;
    int py = p >> 6, px = p & 63;
    float sq = 0.f, sk = 0.f;
    for (int dy = -1; dy <= 1; ++dy)
        for (int dx = -1; dx <= 1; ++dx) {
            int yy = py + dy, xx = px + dx;
            if ((unsigned)yy < 64u && (unsigned)xx < 64u) {
                int o = (b << 12) + (yy << 6) + xx;
                sq += pix2q[o];
                sk += pix2k[o];
            }
        }
    rnq[idx] = 1.f / fmaxf(sqrtf(sq), 1e-12f);
    rnk[idx] = 1.f / fmaxf(sqrtf(sk), 1e-12f);
}

// ---------------- fused MFMA GEMM (K=576: y-3sum in K) + x-3sum + argmax -----
// 256x256 tile, 8 waves (512 thr), wave tile 128(q) x 64(k).
// LDS: 4 classes x 5-slot rings of 64-row x 64-col chunks (8KB) = 160 KB.
//   A-hi @0, A-lo @40960, B-hi @81920, B-lo @122880; chunk c -> slot c%5.
// Per dy: slots dy..dy+3 live; chunk dy+4 prefetched one dy-step ahead
// (counted vmcnt(4), never 0 mid-loop).
// Per kk: B-hi + B-lo cached once (8 regs); per 64-row A-half:
//   {A-hi -> s0 (x B-hi), s1 (x B-lo); A-lo -> s2 (x B-hi)}.
// Short-lived af[4] sets keep peak regs ~200 (R7 spilled at ~225 vs cap 128).
#define WAITV(n_) asm volatile("s_waitcnt vmcnt(" #n_ ")" ::: "memory")
#define SB do { __builtin_amdgcn_s_barrier(); asm volatile("" ::: "memory"); } while (0)

#define AHB 0
#define ALB 40960
#define BHB 81920
#define BLB 122880
#define SLOT5(u_) ((u_) >= 5 ? (u_) - 5 : (u_))

#define ISS4(c_) do { \
    const size_t ro_ = (size_t)((c_) * 64 + rr) * 384; \
    gload_lds16(agb + ro_ +   0 + G16, smem + AHB + ((c_) % 5) * 8192 + t16); \
    gload_lds16(agb + ro_ + 256 + G16, smem + ALB + ((c_) % 5) * 8192 + t16); \
    gload_lds16(bgb + ro_ +   0 + G16, smem + BHB + ((c_) % 5) * 8192 + t16); \
    gload_lds16(bgb + ro_ + 128 + G16, smem + BLB + ((c_) % 5) * 8192 + t16); \
} while (0)

#define GISS4(c_) do { \
    const size_t ro_ = (size_t)((c_) * 64 + rr) * 384; \
    uint4 va_ = make_uint4(0u,0u,0u,0u), vl_ = va_, wh_ = va_, wl_ = va_; \
    if ((unsigned)(arow + (c_) * 64 + rr) < 4096u) { \
        va_ = *(const uint4*)(agb + ro_ + G16); \
        vl_ = *(const uint4*)(agb + ro_ + 256 + G16); } \
    if ((unsigned)(brow + (c_) * 64 + rr) < 4096u) { \
        wh_ = *(const uint4*)(bgb + ro_ + G16); \
        wl_ = *(const uint4*)(bgb + ro_ + 128 + G16); } \
    *(uint4*)(smem + AHB + ((c_) % 5) * 8192 + t16) = va_; \
    *(uint4*)(smem + ALB + ((c_) % 5) * 8192 + t16) = vl_; \
    *(uint4*)(smem + BHB + ((c_) % 5) * 8192 + t16) = wh_; \
    *(uint4*)(smem + BLB + ((c_) % 5) * 8192 + t16) = wl_; \
} while (0)

// 16 MFMA: af[4] x bf[4] -> acc[mo..mo+3][0..3]
#define MM16(af_, bf_, mo_) do { \
    __builtin_amdgcn_s_setprio(1); \
    _Pragma("unroll") \
    for (int mt_ = 0; mt_ < 4; ++mt_) \
        _Pragma("unroll") \
        for (int nt_ = 0; nt_ < 4; ++nt_) \
            acc[(mo_) + mt_][nt_] = __builtin_amdgcn_mfma_f32_16x16x32_bf16( \
                (af_)[mt_], (bf_)[nt_], acc[(mo_) + mt_][nt_], 0, 0, 0); \
    __builtin_amdgcn_s_setprio(0); \
} while (0)

#define LD4(dst_, base_, pk_) do { \
    _Pragma("unroll") \
    for (int q_ = 0; q_ < 4; ++q_) \
        (dst_)[q_] = *(const bf16x8*)((base_) + q_ * 2048 + (pk_)); \
} while (0)

#define DY_STEP(dy_) do { \
    const int sa0_ = SLOT5(wm2 * 2 + (dy_)); \
    const int sa1_ = SLOT5(wm2 * 2 + (dy_) + 1); \
    const int sb_  = SLOT5(wn + (dy_)); \
    const char* Ah0_ = smem + AHB + sa0_ * 8192 + m15 * 128; \
    const char* Ah1_ = smem + AHB + sa1_ * 8192 + m15 * 128; \
    const char* Al0_ = smem + ALB + sa0_ * 8192 + m15 * 128; \
    const char* Al1_ = smem + ALB + sa1_ * 8192 + m15 * 128; \
    const char* Bh_  = smem + BHB + sb_ * 8192 + m15 * 128; \
    const char* Bl_  = smem + BLB + sb_ * 8192 + m15 * 128; \
    _Pragma("unroll") \
    for (int kk = 0; kk < 2; ++kk) { \
        const int pk_ = kk ? posK1 : posK0; \
        bf16x8 bfc[4], bl[4]; \
        LD4(bfc, Bh_, pk_); \
        LD4(bl, Bl_, pk_); \
        { bf16x8 a0[4]; LD4(a0, Ah0_, pk_); MM16(a0, bfc, 0); MM16(a0, bl, 0); } \
        { bf16x8 a1[4]; LD4(a1, Al0_, pk_); MM16(a1, bfc, 0); } \
        { bf16x8 a2[4]; LD4(a2, Ah1_, pk_); MM16(a2, bfc, 4); MM16(a2, bl, 4); } \
        { bf16x8 a3[4]; LD4(a3, Al1_, pk_); MM16(a3, bfc, 4); } \
    } \
} while (0)

__global__ __launch_bounds__(512, 2)
void gemm_fused_kernel(const unsigned short* __restrict__ Aq, const unsigned short* __restrict__ Bq,
                       const float* __restrict__ rnkA,
                       float* __restrict__ part_val, int* __restrict__ part_arg) {
    __shared__ __align__(16) char smem[163840];
    const int tid = threadIdx.x;
    const int lane = tid & 63, wid = tid >> 6;
    const int m15 = lane & 15, quad = lane >> 4;
    const int wn = wid & 3, wm2 = wid >> 2;
    // XCD swizzle: per-b 256 wgs; XCD x owns 2 q-supertiles x all 16 k-tiles.
    const int f = blockIdx.x;
    const int o = ((f & 7) << 5) + (f >> 3);
    const int kt = o & 15, qt = o >> 4;
    const int k0 = kt << 8, q0 = qt << 8;
    const int b = blockIdx.y;
    const int arow = q0 - 64, brow = k0 - 64;
    const char* agb = (const char*)(Aq + (size_t)b * 4096 * 192) + (ptrdiff_t)arow * 384;
    const char* bgb = (const char*)(Bq + (size_t)b * 4096 * 192) + (ptrdiff_t)brow * 384;
    const bool aInt = (q0 >= 64) && (q0 + 320 <= 4096);
    const bool bInt = (k0 >= 64) && (k0 + 320 <= 4096);

    // staging offsets: thread covers 16B of each chunk (512 thr x 16B = 8KB)
    const int rr = tid >> 3;
    const int G16 = ((tid & 7) ^ (rr & 7)) * 16;
    const int t16 = tid * 16;
    // fragment-read pos offsets (row&7 == m15&7 for all frags)
    const int posK0 = (quad ^ (m15 & 7)) * 16;
    const int posK1 = ((4 + quad) ^ (m15 & 7)) * 16;

    floatx4 acc[8][4];
#pragma unroll
    for (int i = 0; i < 8; ++i)
#pragma unroll
        for (int j = 0; j < 4; ++j) acc[i][j] = (floatx4)0.f;

    if (aInt && bInt) {
        ISS4(0); ISS4(1); ISS4(2); ISS4(3);   // 16 gloads: chunks 0..3 (dy0 set)
        ISS4(4);                               // +4: chunk 4 (needed at dy1)
        WAITV(4); SB;                          // chunks 0..3 ready
        DY_STEP(0);                            // reads slots 0..3
        SB;                                    // slot 0 (c0) retired
        ISS4(5);                               // chunk 5 -> slot 0 (needed dy2)
        WAITV(4); SB;                          // chunk 4 ready (c5 in flight)
        DY_STEP(1);                            // reads slots 1..4
        SB; WAITV(0); SB;                      // chunk 5 ready
        DY_STEP(2);                            // reads slots 2..5(=0)
        __syncthreads();                       // rings dead before epilogue
    } else {
        // guarded boundary path: same slots, predicated uint4 + ds_write
        GISS4(0); GISS4(1); GISS4(2); GISS4(3);
        __syncthreads();
        DY_STEP(0);
        __syncthreads();
        GISS4(4);
        __syncthreads();
        DY_STEP(1);
        __syncthreads();
        GISS4(5);
        __syncthreads();
        DY_STEP(2);
        __syncthreads();
    }

    // ---- epilogue: four 64-row (one image row) phases; x-3sum + argmax over
    // the 256-k tile; cross-wave LDS reduce -> 1 partial per (block, q) ----
    float* Csh = (float*)smem;               // [64][261]
    float* bvs = (float*)(smem + 66816);     // [8][64]
    int*   bas = (int*)(smem + 68864);       // [8][64]
    const int q_l = tid & 63;
    const int qr = tid >> 6;                 // k-eighth (0..7), one per wave
    const int c0 = qr * 32;
    const float4 zero4 = make_float4(0.f, 0.f, 0.f, 0.f);

#pragma unroll
    for (int h = 0; h < 4; ++h) {
        if (h) __syncthreads();              // prev-phase readers done
        if (wm2 == (h >> 1)) {
#pragma unroll
            for (int mt2 = 0; mt2 < 4; ++mt2) {
                const int mt = ((h & 1) << 2) + mt2;
#pragma unroll
                for (int nt = 0; nt < 4; ++nt)
#pragma unroll
                    for (int j = 0; j < 4; ++j)
                        Csh[(mt2 * 16 + quad * 4 + j) * 261 + (wn << 6) + nt * 16 + m15] =
                            acc[mt][nt][j];
            }
        }
        __syncthreads();

        const bool qm = q_l > 0;             // qx>0: diag- allowed
        const bool qp = q_l < 63;            // qx<63: diag+ allowed
        const float* rC = Csh + q_l * 261;
        const float* rM = Csh + (q_l - 1) * 261;
        const float* rP = Csh + (q_l + 1) * 261;
        float4 prevm = (qm && c0 > 0) ? *(const float4*)&rM[c0 - 4] : zero4;
        float4 rpj   = qp ? *(const float4*)&rP[c0] : zero4;
        float bv = -INFINITY;
        int ba = 0;
#pragma unroll
        for (int j = 0; j < 8; ++j) {
            int c = c0 + 4 * j;
            float4 cen = *(const float4*)&rC[c];
            float4 rm4 = qm ? *(const float4*)&rM[c] : zero4;
            float4 rp1 = (qp && (c + 4) < 256) ? *(const float4*)&rP[c + 4] : zero4;
            float4 o4;
            o4.x = cen.x + (((c & 63) != 0) ? prevm.w : 0.f) + rpj.y;
            o4.y = cen.y + rm4.x + rpj.z;
            o4.z = cen.z + rm4.y + rpj.w;
            o4.w = cen.w + rm4.z + ((((c + 3) & 63) != 63) ? rp1.x : 0.f);
            float4 rk = *(const float4*)&rnkA[(b << 12) + k0 + c];
            // ascending k + strict > = first-occurrence argmax
            float v0 = o4.x * rk.x; if (v0 > bv) { bv = v0; ba = k0 + c + 0; }
            float v1 = o4.y * rk.y; if (v1 > bv) { bv = v1; ba = k0 + c + 1; }
            float v2 = o4.z * rk.z; if (v2 > bv) { bv = v2; ba = k0 + c + 2; }
            float v3 = o4.w * rk.w; if (v3 > bv) { bv = v3; ba = k0 + c + 3; }
            prevm = rm4;
            rpj = rp1;
        }
        bvs[(qr << 6) + q_l] = bv;
        bas[(qr << 6) + q_l] = ba;
        __syncthreads();
        if (tid < 64) {
            float v = bvs[tid];
            int a = bas[tid];
#pragma unroll
            for (int s = 1; s < 8; ++s) {    // ascending eighth = ascending k
                float v2 = bvs[(s << 6) + tid];
                if (v2 > v) { v = v2; a = bas[(s << 6) + tid]; }
            }
            int q = q0 + (h << 6) + tid;
            part_val[(((b << 4) + kt) << 12) + q] = v;
            part_arg[(((b << 4) + kt) << 12) + q] = a;
        }
    }
}

// ---------------- combine 16 k-slot partials -> final arg + S ----------------
__global__ __launch_bounds__(256)
void argcombine_kernel(const float* __restrict__ part_val, const int* __restrict__ part_arg,
                       const float* __restrict__ rnqA,
                       float* __restrict__ S_out, int* __restrict__ argF) {
    __shared__ float rv[4][64];
    __shared__ int ra[4][64];
    const int tid = threadIdx.x;
    const int qi = tid & 63, sg = tid >> 6;
    const int q = blockIdx.x * 64 + qi;
    const int b = blockIdx.y;
    const int base = (b << 16) + q;
    float bv = -INFINITY; int ba = 0;
#pragma unroll
    for (int i = 0; i < 4; ++i) {            // ascending s = ascending k
        int s = sg * 4 + i;
        float v = part_val[base + (s << 12)];
        int aa = part_arg[base + (s << 12)];
        if (v > bv) { bv = v; ba = aa; }
    }
    rv[sg][qi] = bv; ra[sg][qi] = ba;
    __syncthreads();
    if (tid < 64) {
        float v = rv[0][tid]; int a = ra[0][tid];
#pragma unroll
        for (int s = 1; s < 4; ++s) {        // ascending group: first max wins
            float v2 = rv[s][tid];
            if (v2 > v) { v = v2; a = ra[s][tid]; }
        }
        int idx = (b << 12) + blockIdx.x * 64 + tid;
        S_out[idx] = v * rnqA[idx];
        argF[idx] = a;
    }
}

// ---------------- gather + fold: T[c,y,x] = (1/9) sum_9 VT[a(q)+d][c] --------
__global__ __launch_bounds__(256)
void gatherT_kernel(const float* __restrict__ VT, const int* __restrict__ argF,
                    float* __restrict__ T_out) {
    __shared__ int sArg[192];
    const int y = blockIdx.x, b = blockIdx.y, cg = blockIdx.z;
    const int tid = threadIdx.x;
    if (tid < 192) {
        int r = tid >> 6, x = tid & 63;
        int yy = y - 1 + r;
        sArg[tid] = ((unsigned)yy < 64u) ? argF[(b << 12) + (yy << 6) + x] : 0;
    }
    __syncthreads();

    const int x = tid >> 2, cq = tid & 3;
    const float* Vb = VT + (size_t)b * 4096 * 64 + cg * 16 + cq * 4;
    float ax = 0.f, ay = 0.f, az = 0.f, aw = 0.f;
#pragma unroll
    for (int t = 0; t < 9; ++t) {
        int dy = t / 3 - 1, dx = t % 3 - 1;
        int qy = y - dy, qx = x - dx;
        if ((unsigned)qy < 64u && (unsigned)qx < 64u) {
            int a = sArg[(1 - dy) * 64 + qx];
            int sy = (a >> 6) + dy, sx = (a & 63) + dx;
            if ((unsigned)sy < 64u && (unsigned)sx < 64u) {
                float4 v = *(const float4*)(Vb + (size_t)((sy << 6) + sx) * 64);
                ax += v.x; ay += v.y; az += v.z; aw += v.w;
            }
        }
    }
    float* Tb = T_out + ((size_t)b * 64 + cg * 16 + cq * 4) * HW + (y << 6) + x;
    Tb[0]          = ax * (1.f / 9.f);
    Tb[HW]         = ay * (1.f / 9.f);
    Tb[2 * HW]     = az * (1.f / 9.f);
    Tb[3 * HW]     = aw * (1.f / 9.f);
}

extern "C" void kernel_launch(void* const* d_in, const int* in_sizes, int n_in,
                              void* d_out, int out_size, void* d_ws, size_t ws_size,
                              hipStream_t stream) {
    const float* V = (const float*)d_in[0];
    const float* K = (const float*)d_in[1];
    const float* Q = (const float*)d_in[2];
    float* S_out = (float*)d_out;            // 4*4096
    float* T_out = S_out + 4 * HW;           // 4*64*4096

    char* ws = (char*)d_ws;
    float* pix2q = (float*)(ws + 0);                 // 64 KB
    float* pix2k = (float*)(ws + 65536);
    float* rnq   = (float*)(ws + 131072);
    float* rnk   = (float*)(ws + 196608);
    float* part_val = (float*)(ws + 262144);         // 4*16*4096 f = 1 MB used
    int*   argF  = (int*)(ws + 4456448);             // 64 KB
    int*   part_arg = (int*)(ws + 8650752);          // 1 MB used
    float* VT    = (float*)(ws + 10747904);          // 4*4096*64 f32 = 4 MiB
    unsigned short* Aq = (unsigned short*)(ws + 17039360);   // 4*4096*192 bf16 = 6 MiB
    unsigned short* Bq = (unsigned short*)(ws + 23330816);   // 6 MiB

    prep_kernel<<<dim3(64, 4, 3), 256, 0, stream>>>(Q, K, V, Aq, Bq, VT, pix2q, pix2k);
    patchnorm_kernel<<<64, 256, 0, stream>>>(pix2q, pix2k, rnq, rnk);
    gemm_fused_kernel<<<dim3(256, 4), 512, 0, stream>>>(Aq, Bq, rnk, part_val, part_arg);
    argcombine_kernel<<<dim3(64, 4), 256, 0, stream>>>(part_val, part_arg, rnq, S_out, argF);
    gatherT_kernel<<<dim3(64, 4, 4), 256, 0, stream>>>(VT, argF, T_out);
}

// Round 10
// 199.534 us; speedup vs baseline: 1.0555x; 1.0555x over previous
//
#include <hip/hip_runtime.h>
#include <math.h>

#define HW 4096   // H*W = 64*64; B=4, C=64, H=W=64, L=4096

typedef short bf16x8 __attribute__((ext_vector_type(8)));
typedef float floatx4 __attribute__((ext_vector_type(4)));
typedef unsigned short u16x8 __attribute__((ext_vector_type(8)));

__device__ __forceinline__ unsigned short f2bf_rne(float x) {
    unsigned int u = __float_as_uint(x);
    unsigned int r = (u + 0x7FFFu + ((u >> 16) & 1u)) >> 16;
    return (unsigned short)r;
}
__device__ __forceinline__ float bf2f(unsigned short h) {
    return __uint_as_float(((unsigned int)h) << 16);
}

// async global->LDS, 16 B per lane; LDS dest is wave-uniform base + lane*16.
__device__ __forceinline__ void gload_lds16(const void* gptr, void* lptr) {
    auto g = (const __attribute__((address_space(1))) unsigned int*)(unsigned long long)(gptr);
    auto l = (__attribute__((address_space(3))) unsigned int*)(unsigned int)(unsigned long long)(lptr);
    __builtin_amdgcn_global_load_lds(g, l, 16, 0, 0);
}

// ---------------- prep: z=0 Q / z=1 K: split fp32 -> bf16 (hi,lo), transpose
// to [p][c], fused per-pixel squared norms. Row layout (192 shorts):
//   Aq[b][p] = [Qh | UNINIT | Ql],  Bq[b][p] = [Kh | Kl | UNINIT]
// (slice1 of A and slice2 of B are NEVER written -- all readers must use
//  only A slices {0,2} and B slices {0,1}; R9's boundary path violated this.)
// z=2: transpose V -> VT[b][p][c] (f32) so gatherT reads channels contiguous.
__global__ __launch_bounds__(256)
void prep_kernel(const float* __restrict__ Q, const float* __restrict__ K,
                 const float* __restrict__ V,
                 unsigned short* __restrict__ Aq, unsigned short* __restrict__ Bq,
                 float* __restrict__ VT,
                 float* __restrict__ pix2q, float* __restrict__ pix2k) {
    __shared__ float sT[64][65];
    const int tid = threadIdx.x;
    const int p0 = blockIdx.x * 64;
    const int b = blockIdx.y;
    const int which = blockIdx.z;            // 0=Q, 1=K, 2=V
    const float* __restrict__ src = (which == 0) ? Q : ((which == 1) ? K : V);

#pragma unroll
    for (int it = 0; it < 16; ++it) {
        int idx = it * 256 + tid;
        int c = idx >> 6, x = idx & 63;
        sT[c][x] = src[((size_t)b * 64 + c) * HW + p0 + x];
    }
    __syncthreads();
    const int pp = tid >> 2, qt = tid & 3;

    if (which == 2) {                        // V: pure f32 transpose
        float* dst = VT + ((size_t)b * 4096 + p0 + pp) * 64 + qt * 16;
#pragma unroll
        for (int j = 0; j < 4; ++j) {
            float4 v = make_float4(sT[qt * 16 + 4 * j + 0][pp], sT[qt * 16 + 4 * j + 1][pp],
                                   sT[qt * 16 + 4 * j + 2][pp], sT[qt * 16 + 4 * j + 3][pp]);
            *(float4*)(dst + 4 * j) = v;
        }
        return;
    }

    const int isK = which;
    unsigned short* __restrict__ dst = isK ? Bq : Aq;
    float* __restrict__ pix2 = isK ? pix2k : pix2q;
    const size_t base = ((size_t)b * 4096 + p0 + pp) * 192;
    {
        float sq = 0.f;
        u16x8 hv[2], lv[2];
#pragma unroll
        for (int g = 0; g < 2; ++g)
#pragma unroll
            for (int j = 0; j < 8; ++j) {
                int c = qt * 16 + g * 8 + j;
                float x = sT[c][pp];
                sq = fmaf(x, x, sq);
                unsigned short h = f2bf_rne(x);
                hv[g][j] = h;
                lv[g][j] = f2bf_rne(x - bf2f(h));
            }
        sq += __shfl_xor(sq, 1, 64);
        sq += __shfl_xor(sq, 2, 64);
        if (qt == 0) pix2[(b << 12) + p0 + pp] = sq;
#pragma unroll
        for (int g = 0; g < 2; ++g) {
            int co = qt * 16 + g * 8;
            *(u16x8*)(dst + base + co)                     = hv[g];  // hi slice
            *(u16x8*)(dst + base + (isK ? 64 : 128) + co)  = lv[g];  // lo slice
        }
    }
}

// ---------------- fused MFMA GEMM (K=576: y-3sum in K) + x-3sum + argmax -----
// Slice identities: seg0 = Qh.Kh, seg1 = Qh.Kl, seg2 = Ql.Kh.
// Step order (s0,s1,s2) per dy:
//   s0 = Qh.Kh : A,B from LDS; cache A frags->afc, B frags->bfc (1 dy live)
//   s1 = Qh.Kl : A = afc (no LDS), B = Bl from LDS
//   s2 = Ql.Kh : A = Al from LDS, B = bfc (no LDS; Kh' never staged)
// 16 staged chunks, 96 ds_read_b128/wave.  LDS: A 5 | B 5 slots = 80 KB.
// rnk computed INLINE in the epilogue from pix2k (patchnorm kernel removed).
// BOUNDARY PATH FIX (R9 bug): stage A slice {0,0,2}[seg] and B slice
// {0,1,0}[seg] -- slice1 of A / slice2 of B are uninitialized in prep.
#define WAITV(n_) asm volatile("s_waitcnt vmcnt(" #n_ ")" ::: "memory")
#define PBAR(n_) do { WAITV(n_); __builtin_amdgcn_s_barrier(); \
                      asm volatile("" ::: "memory"); } while (0)

#define ISSUE_A(c_, sg_, slot_) do { \
    const char* g_ = Aqb + (size_t)(q0 - 64 + (c_) * 64) * 384 + (sg_) * 128; \
    gload_lds16(g_ + g0off, smem + (slot_) * 8192 + l0off); \
    gload_lds16(g_ + g1off, smem + (slot_) * 8192 + l1off); \
} while (0)
#define ISSUE_B(c_, sg_, slot_) do { \
    const char* g_ = Bqb + (size_t)(k0 - 64 + (c_) * 64) * 384 + (sg_) * 128; \
    gload_lds16(g_ + g0off, smemB + (slot_) * 8192 + l0off); \
    gload_lds16(g_ + g1off, smemB + (slot_) * 8192 + l1off); \
} while (0)

#define MM16(af_, bfr_) do { \
    __builtin_amdgcn_s_setprio(1); \
    _Pragma("unroll") \
    for (int mt = 0; mt < 4; ++mt) \
        _Pragma("unroll") \
        for (int nt = 0; nt < 4; ++nt) \
            acc[mt][nt] = __builtin_amdgcn_mfma_f32_16x16x32_bf16( \
                (af_)[mt], (bfr_)[nt], acc[mt][nt], 0, 0, 0); \
    __builtin_amdgcn_s_setprio(0); \
} while (0)

// s0: A slot (wm+D), B slot (wn+D); cache both fragment sets
#define STEP_S0(D_) do { \
    const char* As_ = smem + (wm + (D_)) * 8192; \
    const char* Bs_ = smemB + (wn + (D_)) * 8192; \
    _Pragma("unroll") \
    for (int kk = 0; kk < 2; ++kk) { \
        const int pk_ = kk ? posK1 : posK0; \
        _Pragma("unroll") \
        for (int mt = 0; mt < 4; ++mt) \
            afc[kk][mt] = *(const bf16x8*)(As_ + mt * 2048 + rowB + pk_); \
        _Pragma("unroll") \
        for (int nt = 0; nt < 4; ++nt) \
            bfc[kk][nt] = *(const bf16x8*)(Bs_ + nt * 2048 + rowB + pk_); \
        MM16(afc[kk], bfc[kk]); \
    } \
} while (0)

// s1: A from afc; B (Kl) slot {3,4,0,1}[wn+D]
#define STEP_S1(D_) do { \
    const int xb_ = wn + (D_); \
    const char* Bs_ = smemB + (xb_ < 2 ? xb_ + 3 : xb_ - 2) * 8192; \
    _Pragma("unroll") \
    for (int kk = 0; kk < 2; ++kk) { \
        const int pk_ = kk ? posK1 : posK0; \
        bf16x8 bfr[4]; \
        _Pragma("unroll") \
        for (int nt = 0; nt < 4; ++nt) \
            bfr[nt] = *(const bf16x8*)(Bs_ + nt * 2048 + rowB + pk_); \
        MM16(afc[kk], bfr); \
    } \
} while (0)

// s2: A (Ql) slot {4,0,4,1}[wm+D]; B from bfc
#define STEP_S2(D_) do { \
    const int xa_ = wm + (D_); \
    const char* As_ = smem + ((xa_ & 1) ? (xa_ >> 1) : 4) * 8192; \
    _Pragma("unroll") \
    for (int kk = 0; kk < 2; ++kk) { \
        const int pk_ = kk ? posK1 : posK0; \
        bf16x8 af[4]; \
        _Pragma("unroll") \
        for (int mt = 0; mt < 4; ++mt) \
            af[mt] = *(const bf16x8*)(As_ + mt * 2048 + rowB + pk_); \
        MM16(af, bfc[kk]); \
    } \
} while (0)

__global__ __launch_bounds__(256, 2)
void gemm_fused_kernel(const unsigned short* __restrict__ Aq, const unsigned short* __restrict__ Bq,
                       const float* __restrict__ pix2k,
                       float* __restrict__ part_val, int* __restrict__ part_arg) {
    __shared__ __align__(16) char smem[81920];   // A 5x8K | B 5x8K; epilogue aliases A region
    char* const smemB = smem + 40960;
    const int tid = threadIdx.x;
    const int lane = tid & 63, wid = tid >> 6;
    const int m15 = lane & 15, quad = lane >> 4;
    const int wm = wid & 1, wn = wid >> 1;
    // XCD-chunked swizzle: per-b 1024 wgs; XCD x owns contiguous original
    // range [x*128,(x+1)*128) = 4 q-tiles x all 32 k-tiles (~2MB < 4MB L2).
    const int f = blockIdx.x + (blockIdx.y << 5);
    const int o = ((f & 7) << 7) + (f >> 3);
    const int kt = o & 31, qt = o >> 5;
    const int k0 = kt << 7;
    const int q0 = qt << 7;
    const int b = blockIdx.z;
    const char* Aqb = (const char*)(Aq + (size_t)b * 4096 * 192);
    const char* Bqb = (const char*)(Bq + (size_t)b * 4096 * 192);
    const bool aInt = (q0 >= 64) && (q0 <= 4096 - 192);   // A slab fully in-image
    const bool bInt = (k0 >= 64) && (k0 <= 4096 - 192);

    // per-thread staging offsets (chunk = 64 rows x 8 pos x 16B; pos^=(row&7))
    const int rr0 = tid >> 3, ps = tid & 7;
    const int g0off = rr0 * 384 + (ps ^ (rr0 & 7)) * 16;
    const int l0off = tid * 16;
    const int rr1 = (256 + tid) >> 3;
    const int g1off = rr1 * 384 + (ps ^ (rr1 & 7)) * 16;
    const int l1off = (256 + tid) * 16;
    // per-thread fragment-read offsets
    const int rowB = m15 * 128;
    const int posK0 = (quad ^ (m15 & 7)) * 16;
    const int posK1 = ((4 + quad) ^ (m15 & 7)) * 16;

    floatx4 acc[4][4];
#pragma unroll
    for (int i = 0; i < 4; ++i)
#pragma unroll
        for (int j = 0; j < 4; ++j) acc[i][j] = (floatx4)0.f;

    bf16x8 afc[2][4];   // s0 A-frag cache -> s1 (one dy live)
    bf16x8 bfc[2][4];   // s0 B-frag cache -> s2 (one dy live)

    if (aInt && bInt) {
        // chunk issue ids: c1 Ah0, c2 Ah1, c3 Bh0, c4 Bh1, c5 Ah2, c6 Bh2,
        // c7 Ah3, c8 Bl0, c9 Bl1, c10 Al0 | t1: c11 Al1, c12 Bl2 | t2: c13 Bh3
        // t3: c14 Al2 | t4: c15 Bl3 | t5: c16 Al3.   (2 loads/thread/chunk)
        ISSUE_A(0, 0, 0); ISSUE_A(1, 0, 1); ISSUE_B(0, 0, 0); ISSUE_B(1, 0, 1);
        ISSUE_A(2, 0, 2); ISSUE_B(2, 0, 2); ISSUE_A(3, 0, 3); ISSUE_B(0, 1, 3);
        ISSUE_B(1, 1, 4); ISSUE_A(0, 2, 4);
        PBAR(12);                                      STEP_S0(0);  // needs c1-c4
        PBAR(2);  ISSUE_A(1, 2, 0); ISSUE_B(2, 1, 0); STEP_S1(0);  // needs c8,c9
        PBAR(2);  ISSUE_B(3, 0, 3);                   STEP_S2(0);  // needs c10,c11
        PBAR(14); ISSUE_A(2, 2, 4);                   STEP_S0(1);  // needs c2,c4,c5,c6
        PBAR(4);  ISSUE_B(3, 1, 1);                   STEP_S1(1);  // needs c9,c12
        PBAR(2);  ISSUE_A(3, 2, 1);                   STEP_S2(1);  // needs c11,c14
        PBAR(6);                                      STEP_S0(2);  // needs c5,c6,c7,c13
        PBAR(2);                                      STEP_S1(2);  // needs c12,c15
        PBAR(0);                                      STEP_S2(2);  // needs c14,c16
        __syncthreads();   // slabs dead before epilogue overwrites
    } else {
        // ---- legacy guarded path (boundary blocks): stage slab per seg.
        // FIX: slice offsets are seg-SEMANTIC, reading only written slices:
        //   A: {Qh, Qh, Ql}[seg] -> byte offset {0, 0, 256}
        //   B: {Kh, Kl, Kh}[seg] -> byte offset {0, 128, 0}
        for (int seg = 0; seg < 3; ++seg) {
            const char* abL = Aqb + (size_t)(q0 - 64) * 384 + ((seg == 2) ? 256 : 0);
            const char* bbL = Bqb + (size_t)(k0 - 64) * 384 + ((seg == 1) ? 128 : 0);
            if (aInt) {
#pragma unroll
                for (int it = 0; it < 8; ++it) {
                    int slot = it * 256 + tid;
                    int row = slot >> 3, pos = slot & 7;
                    int G = pos ^ (row & 7);
                    gload_lds16(abL + (size_t)row * 384 + G * 16, smem + slot * 16);
                }
            } else {
#pragma unroll
                for (int it = 0; it < 8; ++it) {
                    int slot = it * 256 + tid;
                    int row = slot >> 3, pos = slot & 7;
                    int G = pos ^ (row & 7);
                    uint4 v = make_uint4(0u, 0u, 0u, 0u);
                    if ((unsigned)(q0 - 64 + row) < 4096u)
                        v = *(const uint4*)(abL + (size_t)row * 384 + G * 16);
                    *(uint4*)(smem + slot * 16) = v;
                }
            }
            if (bInt) {
#pragma unroll
                for (int it = 0; it < 8; ++it) {
                    int slot = it * 256 + tid;
                    int row = slot >> 3, pos = slot & 7;
                    int G = pos ^ (row & 7);
                    gload_lds16(bbL + (size_t)row * 384 + G * 16, smemB + slot * 16);
                }
            } else {
#pragma unroll
                for (int it = 0; it < 8; ++it) {
                    int slot = it * 256 + tid;
                    int row = slot >> 3, pos = slot & 7;
                    int G = pos ^ (row & 7);
                    uint4 v = make_uint4(0u, 0u, 0u, 0u);
                    if ((unsigned)(k0 - 64 + row) < 4096u)
                        v = *(const uint4*)(bbL + (size_t)row * 384 + G * 16);
                    *(uint4*)(smemB + slot * 16) = v;
                }
            }
            __syncthreads();
            STEP_S0(0); STEP_S0(1); STEP_S0(2);
            __syncthreads();
        }
    }

    // ---- epilogue: inline rnk (3x3 pix2k box from L2 -> LDS), then two
    // 64-row phases; x-3sum + max/argmax over the 128-k tile; cross-quarter
    // LDS reduce -> one partial per (block, q) ----
    float* Csh = (float*)smem;               // [64][133] = 34048 B
    float* bvs = (float*)(smem + 34816);     // [4][64]
    int*   bas = (int*)(smem + 35840);       // [4][64]
    float* Lrnk = (float*)(smem + 36864);    // [128]
    if (tid < 128) {                         // rnk for k0..k0+127 (2 image rows)
        int k = k0 + tid;
        int py = k >> 6, px = k & 63;
        float sk = 0.f;
        for (int dy = -1; dy <= 1; ++dy)
            for (int dx = -1; dx <= 1; ++dx) {
                int yy = py + dy, xx = px + dx;
                if ((unsigned)yy < 64u && (unsigned)xx < 64u)
                    sk += pix2k[(b << 12) + (yy << 6) + xx];
            }
        Lrnk[tid] = 1.f / fmaxf(sqrtf(sk), 1e-12f);
    }
    const int q_l = tid & 63;
    const int qr = tid >> 6;                 // k-quarter (0..3), one per wave
    const int c0 = qr * 32;
    const float4 zero4 = make_float4(0.f, 0.f, 0.f, 0.f);

#pragma unroll
    for (int h = 0; h < 2; ++h) {
        if (h) __syncthreads();              // phase-0 readers done before overwrite
        if (wm == h) {
#pragma unroll
            for (int mt = 0; mt < 4; ++mt)
#pragma unroll
                for (int nt = 0; nt < 4; ++nt)
#pragma unroll
                    for (int j = 0; j < 4; ++j)
                        Csh[(mt * 16 + quad * 4 + j) * 133 + wn * 64 + nt * 16 + m15] =
                            acc[mt][nt][j];
        }
        __syncthreads();                     // also orders Lrnk writes (h==0)

        const bool qm = q_l > 0;             // qx>0: diag- allowed
        const bool qp = q_l < 63;            // qx<63: diag+ allowed
        const float* rC = Csh + q_l * 133;
        const float* rM = Csh + (q_l - 1) * 133;
        const float* rP = Csh + (q_l + 1) * 133;
        float4 prevm = (qm && c0 > 0) ? *(const float4*)&rM[c0 - 4] : zero4;
        float4 rpj   = qp ? *(const float4*)&rP[c0] : zero4;
        float bv = -INFINITY;
        int ba = 0;
#pragma unroll
        for (int j = 0; j < 8; ++j) {
            int c = c0 + 4 * j;
            float4 cen = *(const float4*)&rC[c];
            float4 rm4 = qm ? *(const float4*)&rM[c] : zero4;
            float4 rp1 = (qp && (c + 4) < 128) ? *(const float4*)&rP[c + 4] : zero4;
            float4 o4;
            o4.x = cen.x + (((c & 63) != 0) ? prevm.w : 0.f) + rpj.y;
            o4.y = cen.y + rm4.x + rpj.z;
            o4.z = cen.z + rm4.y + rpj.w;
            o4.w = cen.w + rm4.z + ((((c + 3) & 63) != 63) ? rp1.x : 0.f);
            float4 rk = *(const float4*)&Lrnk[c];
            // ascending k + strict > = first-occurrence argmax
            float v0 = o4.x * rk.x; if (v0 > bv) { bv = v0; ba = k0 + c + 0; }
            float v1 = o4.y * rk.y; if (v1 > bv) { bv = v1; ba = k0 + c + 1; }
            float v2 = o4.z * rk.z; if (v2 > bv) { bv = v2; ba = k0 + c + 2; }
            float v3 = o4.w * rk.w; if (v3 > bv) { bv = v3; ba = k0 + c + 3; }
            prevm = rm4;
            rpj = rp1;
        }
        bvs[(qr << 6) + q_l] = bv;
        bas[(qr << 6) + q_l] = ba;
        __syncthreads();
        if (tid < 64) {
            float v = bvs[tid];
            int a = bas[tid];
#pragma unroll
            for (int s = 1; s < 4; ++s) {    // ascending quarter = ascending k
                float v2 = bvs[(s << 6) + tid];
                if (v2 > v) { v = v2; a = bas[(s << 6) + tid]; }
            }
            int q = q0 + h * 64 + tid;
            part_val[(((b << 5) + kt) << 12) + q] = v;
            part_arg[(((b << 5) + kt) << 12) + q] = a;
        }
    }
}

// ---------------- gather + fold + fused combine + S ----------------
// Per block (y, b, cg): combine the 32 k-slot partials for arg rows y-1..y+1
// (ascending s = ascending k -> first-occurrence argmax), write S for row y
// (cg==0; rnq computed inline from pix2q), then
// T[c,y,x] = (1/9) sum_9 VT[a(q)+d][c] with channel-contiguous VT.
__global__ __launch_bounds__(256)
void gatherT_kernel(const float* __restrict__ VT,
                    const float* __restrict__ part_val, const int* __restrict__ part_arg,
                    const float* __restrict__ pix2q,
                    float* __restrict__ S_out, float* __restrict__ T_out) {
    __shared__ int sArg[192];
    const int y = blockIdx.x, b = blockIdx.y, cg = blockIdx.z;
    const int tid = threadIdx.x;
    if (tid < 192) {
        int r = tid >> 6, x = tid & 63;
        int yy = y - 1 + r;
        int a = 0;
        if ((unsigned)yy < 64u) {
            int base = (b << 17) + (yy << 6) + x;   // part[(b*32+s)][q]
            float bv = -INFINITY; int ba = 0;
#pragma unroll 8
            for (int s = 0; s < 32; ++s) {   // ascending s = ascending k
                float v = part_val[base + (s << 12)];
                int aa = part_arg[base + (s << 12)];
                if (v > bv) { bv = v; ba = aa; }
            }
            a = ba;
            if (r == 1 && cg == 0) {         // S for row y, rnq inline
                float sq = 0.f;
                for (int dy = -1; dy <= 1; ++dy)
                    for (int dx = -1; dx <= 1; ++dx) {
                        int y2 = yy + dy, x2 = x + dx;
                        if ((unsigned)y2 < 64u && (unsigned)x2 < 64u)
                            sq += pix2q[(b << 12) + (y2 << 6) + x2];
                    }
                S_out[(b << 12) + (yy << 6) + x] =
                    bv * (1.f / fmaxf(sqrtf(sq), 1e-12f));
            }
        }
        sArg[tid] = a;
    }
    __syncthreads();

    const int x = tid >> 2, cq = tid & 3;
    const float* Vb = VT + (size_t)b * 4096 * 64 + cg * 16 + cq * 4;
    float ax = 0.f, ay = 0.f, az = 0.f, aw = 0.f;
#pragma unroll
    for (int t = 0; t < 9; ++t) {
        int dy = t / 3 - 1, dx = t % 3 - 1;
        int qy = y - dy, qx = x - dx;
        if ((unsigned)qy < 64u && (unsigned)qx < 64u) {
            int a = sArg[(1 - dy) * 64 + qx];
            int sy = (a >> 6) + dy, sx = (a & 63) + dx;
            if ((unsigned)sy < 64u && (unsigned)sx < 64u) {
                float4 v = *(const float4*)(Vb + (size_t)((sy << 6) + sx) * 64);
                ax += v.x; ay += v.y; az += v.z; aw += v.w;
            }
        }
    }
    float* Tb = T_out + ((size_t)b * 64 + cg * 16 + cq * 4) * HW + (y << 6) + x;
    Tb[0]          = ax * (1.f / 9.f);
    Tb[HW]         = ay * (1.f / 9.f);
    Tb[2 * HW]     = az * (1.f / 9.f);
    Tb[3 * HW]     = aw * (1.f / 9.f);
}

extern "C" void kernel_launch(void* const* d_in, const int* in_sizes, int n_in,
                              void* d_out, int out_size, void* d_ws, size_t ws_size,
                              hipStream_t stream) {
    const float* V = (const float*)d_in[0];
    const float* K = (const float*)d_in[1];
    const float* Q = (const float*)d_in[2];
    float* S_out = (float*)d_out;            // 4*4096
    float* T_out = S_out + 4 * HW;           // 4*64*4096

    char* ws = (char*)d_ws;
    float* pix2q = (float*)(ws + 0);                 // 64 KB
    float* pix2k = (float*)(ws + 65536);             // 64 KB
    float* part_val = (float*)(ws + 262144);         // 4*32*4096 f = 2 MB used
    int*   part_arg = (int*)(ws + 8650752);          // 2 MB used
    float* VT    = (float*)(ws + 10747904);          // 4*4096*64 f32 = 4 MiB
    unsigned short* Aq = (unsigned short*)(ws + 17039360);   // 4*4096*192 bf16 = 6 MiB
    unsigned short* Bq = (unsigned short*)(ws + 23330816);   // 6 MiB

    prep_kernel<<<dim3(64, 4, 3), 256, 0, stream>>>(Q, K, V, Aq, Bq, VT, pix2q, pix2k);
    gemm_fused_kernel<<<dim3(32, 32, 4), 256, 0, stream>>>(Aq, Bq, pix2k, part_val, part_arg);
    gatherT_kernel<<<dim3(64, 4, 4), 256, 0, stream>>>(VT, part_val, part_arg, pix2q, S_out, T_out);
}